// Round 7
// baseline (457.435 us; speedup 1.0000x reference)
//
#include <hip/hip_runtime.h>

#define DIMX 512
#define HEADSX 4
#define DHX 128
#define CHX 16
#define NCX 128
#define SX 2048
#define BX 2
#define BHX 8
#define PADX 520   // xs LDS row pad (ushorts)
#define PADF 136   // stage LDS row pad (ushorts)
#define NBAT 4     // scan batches
#define BATCH 32   // chunks per batch

typedef unsigned short ushort_t;
typedef unsigned int uint_t;
typedef short bf16x8 __attribute__((ext_vector_type(8)));
typedef float f32x4 __attribute__((ext_vector_type(4)));

__device__ __forceinline__ float sigmoidf_(float z){ return 1.0f/(1.0f + __expf(-z)); }

// fp32 -> bf16 round-to-nearest-even
__device__ __forceinline__ ushort_t f2bf(float f){
  uint_t u = __float_as_uint(f);
  return (ushort_t)((u + 0x7FFFu + ((u >> 16) & 1u)) >> 16);
}
__device__ __forceinline__ uint_t pk2(float a, float b){
  return (uint_t)f2bf(a) | ((uint_t)f2bf(b) << 16);
}

// ---------------- K-prep: bf16 weight layouts + premultiplied stat tables ----------------
__global__ __launch_bounds__(256) void k_prep(const float* __restrict__ Wkv,
    const float* __restrict__ w0, const float* __restrict__ w1,
    const float* __restrict__ scale,
    const float* __restrict__ Wstep, const float* __restrict__ Wmom,
    const float* __restrict__ Wdec,
    ushort_t* __restrict__ WkvT, ushort_t* __restrict__ w0T,
    ushort_t* __restrict__ w1T, ushort_t* __restrict__ w1n,
    float* __restrict__ wfsS, float* __restrict__ wfsM, float* __restrict__ wfsD,
    uint_t* done){
  int blk = blockIdx.x; int tid = threadIdx.x;
  if (blk < 64){
    int h = blk >> 4, kt = blk & 15;
    __shared__ ushort_t tile[256][33];   // [col][kk], +1 pad
    for (int i=tid; i<8192; i+=256){
      int kk = i >> 8, col = i & 255;    // coalesced read
      int wcol = (col < 128) ? (h*128 + col) : (384 + h*128 + col);
      float v = Wkv[(size_t)(kt*32+kk)*1024 + wcol];
      tile[col][kk] = f2bf(v);
    }
    __syncthreads();
    for (int i=tid; i<8192; i+=256){
      int col = i >> 5, kk = i & 31;     // coalesced write
      WkvT[(((size_t)h*16 + kt)*256 + col)*32 + kk] = tile[col][kk];
    }
  } else if (blk < 72){
    int bh = blk - 64;
    size_t base = (size_t)bh*16384;
    for (int i=tid; i<16384; i+=256){
      int r = i >> 7, c = i & 127;
      w0T[base + i] = f2bf(w0[base + (size_t)c*128 + r]);
      w1T[base + i] = f2bf(w1[base + (size_t)c*128 + r]);
      w1n[base + i] = f2bf(w1[base + i]);
    }
  } else {
    for (int i=tid; i<2048; i+=256){
      int d = i & 511, h = i >> 9;
      float sc = scale[d];
      wfsS[i] = sc * Wstep[d*4 + h];
      wfsM[i] = sc * Wmom [d*4 + h];
      wfsD[i] = sc * Wdec [d*4 + h];
    }
    // reset pipeline counters (agent-scope store -> visible at L3 coherence point)
    if (tid < BHX*NBAT)
      __hip_atomic_store(&done[tid], 0u, __ATOMIC_RELAXED, __HIP_MEMORY_SCOPE_AGENT);
  }
}

// ---------------- K-pipe: producer/consumer pipeline ----------------
// 512 blocks x 256 threads, __launch_bounds__(256,2): LDS 34KB, VGPR<=256 ->
// 2 blocks/CU guaranteed -> ALL 512 blocks co-resident (no spin deadlock).
// Blocks 0..255 (producers): block (bh = blk&7, g = blk>>3) produces chunks
//   t = g + 32*it, it=0..3 (fused5 4-wave body). After each chunk: barrier
//   (drains stores to L2) + release atomicAdd on done[bh][it] (wbL2 + L3 RMW).
// Blocks 256..511 (consumers): 4 scan3 waves each; batch bat waits
//   done[bh][bat]==32 (relaxed L3 polls, no cache thrash), then ONE agent
//   acquire fence, then scans chunks [32*bat, 32*bat+32) exactly as scan3.
// Producer compute hides under the scan's HBM write stream.
__global__ __launch_bounds__(256, 2) void k_pipe(const float* __restrict__ seq,
    const float* __restrict__ scale,
    const float* __restrict__ wfsS, const float* __restrict__ wfsM,
    const float* __restrict__ wfsD,
    const ushort_t* __restrict__ WkvT, const ushort_t* __restrict__ w0T,
    const ushort_t* __restrict__ w1T, const ushort_t* __restrict__ w1n,
    ushort_t* __restrict__ fac0, ushort_t* __restrict__ fac1,
    float* __restrict__ momw, float* __restrict__ decw,
    uint_t* done, float* __restrict__ out){
  __shared__ __align__(16) ushort_t xs[16*PADX];
  __shared__ __align__(16) ushort_t ks[16*PADF];
  __shared__ __align__(16) ushort_t as_[16*PADF];
  __shared__ __align__(16) ushort_t dp_[16*PADF];
  __shared__ __align__(16) ushort_t dh_[16*PADF];
  __shared__ float lr_s[16];
  __shared__ float red_m[4], red_d[4];
  int blk = blockIdx.x;
  int tid = threadIdx.x;
  const f32x4 zero = {0.f,0.f,0.f,0.f};

  if (blk < 256){
    // ================= producer =================
    int bh = blk & 7, g = blk >> 3;
    int b = bh >> 2, h = bh & 3;
    int wv = tid >> 6, lane = tid & 63;
    int quad = lane >> 4, nl = lane & 15;

    for (int it=0; it<4; it++){
      int t = g + 32*it;
      int bt = bh*NCX + t;

      // ---- phase 0: stats + normalized bf16 x into LDS
      {
        int c = tid >> 4, sl = tid & 15;
        const float4* sr = (const float4*)(seq + ((size_t)(b*SX + t*CHX) + c)*DIMX);
        const float4* scl = (const float4*)scale;
        const float4* wS = (const float4*)(wfsS + h*512);
        const float4* wM = (const float4*)(wfsM + h*512);
        const float4* wD = (const float4*)(wfsD + h*512);
        float4 q[8];
        #pragma unroll
        for (int jj=0; jj<8; jj++) q[jj] = sr[sl + 16*jj];
        float ss=0.f, lp=0.f, pm=0.f, pd=0.f;
        #pragma unroll
        for (int jj=0; jj<8; jj++){
          float4 a = q[jj];
          float4 s4 = wS[sl+16*jj], m4 = wM[sl+16*jj], d4 = wD[sl+16*jj];
          ss += a.x*a.x + a.y*a.y + a.z*a.z + a.w*a.w;
          lp += a.x*s4.x + a.y*s4.y + a.z*s4.z + a.w*s4.w;
          pm += a.x*m4.x + a.y*m4.y + a.z*m4.z + a.w*m4.w;
          pd += a.x*d4.x + a.y*d4.y + a.z*d4.z + a.w*d4.w;
        }
        #pragma unroll
        for (int mk=1; mk<16; mk<<=1){
          ss += __shfl_xor(ss,mk,64); lp += __shfl_xor(lp,mk,64);
          pm += __shfl_xor(pm,mk,64); pd += __shfl_xor(pd,mk,64);
        }
        float rs = 1.0f / sqrtf(ss*(1.0f/DIMX) + 1e-6f);
        if (sl==0) lr_s[c] = 0.01f * sigmoidf_(rs*lp);
        float pmr = rs*pm, pdr = rs*pd;
        #pragma unroll
        for (int mk=16; mk<64; mk<<=1){ pmr += __shfl_xor(pmr,mk,64); pdr += __shfl_xor(pdr,mk,64); }
        if (lane==0){ red_m[wv]=pmr; red_d[wv]=pdr; }
        #pragma unroll
        for (int jj=0; jj<8; jj++){
          float4 s4 = scl[sl+16*jj];
          uint2 u;
          u.x = pk2(q[jj].x*rs*s4.x, q[jj].y*rs*s4.y);
          u.y = pk2(q[jj].z*rs*s4.z, q[jj].w*rs*s4.w);
          *(uint2*)&xs[c*PADX + (sl+16*jj)*4] = u;
        }
      }
      __syncthreads();   // (1)
      if (tid==0){
        momw[bt] = sigmoidf_((red_m[0]+red_m[1]+red_m[2]+red_m[3])*(1.0f/CHX));
        decw[bt] = 1.0f - sigmoidf_((red_d[0]+red_d[1]+red_d[2]+red_d[3])*(1.0f/CHX));
      }

      // ---- KV gemm: M=16, N=256 (k|v), K=512
      f32x4 kacc[2] = {zero,zero};
      f32x4 vacc[2] = {zero,zero};
      const ushort_t* wkvh = WkvT + (size_t)h*16*256*32;
      for (int kt=0; kt<16; kt++){
        bf16x8 Af = *(const bf16x8*)&xs[nl*PADX + kt*32 + quad*8];
        #pragma unroll
        for (int s=0; s<2; s++){
          int ktile = 2*wv + s;
          bf16x8 Bk = *(const bf16x8*)&wkvh[((size_t)kt*256 + (ktile*16+nl))*32 + quad*8];
          kacc[s] = __builtin_amdgcn_mfma_f32_16x16x32_bf16(Af, Bk, kacc[s], 0,0,0);
          int vtile = 8 + 2*wv + s;
          bf16x8 Bv = *(const bf16x8*)&wkvh[((size_t)kt*256 + (vtile*16+nl))*32 + quad*8];
          vacc[s] = __builtin_amdgcn_mfma_f32_16x16x32_bf16(Af, Bv, vacc[s], 0,0,0);
        }
      }
      #pragma unroll
      for (int s=0;s<2;s++){
        #pragma unroll
        for (int r=0;r<4;r++)
          ks[(quad*4+r)*PADF + 32*wv + 16*s + nl] = f2bf(kacc[s][r]);
      }
      __syncthreads();   // (2)

      // ---- gemm1: h = k @ w0
      const ushort_t* w0b = w0T + (size_t)bh*16384;
      f32x4 hacc[2] = {zero,zero};
      #pragma unroll
      for (int kt=0; kt<4; kt++){
        bf16x8 Af = *(const bf16x8*)&ks[nl*PADF + kt*32 + quad*8];
        #pragma unroll
        for (int s=0; s<2; s++){
          int n0 = (2*wv+s)*16;
          bf16x8 Bf = *(const bf16x8*)&w0b[(size_t)(n0+nl)*128 + kt*32 + quad*8];
          hacc[s] = __builtin_amdgcn_mfma_f32_16x16x32_bf16(Af, Bf, hacc[s], 0,0,0);
        }
      }
      float sp[2][4];
      #pragma unroll
      for (int s=0;s<2;s++){
        #pragma unroll
        for (int r=0;r<4;r++){
          float hh = hacc[s][r];
          float sg = sigmoidf_(hh);
          sp[s][r] = sg*(1.0f + hh*(1.0f-sg));
          as_[(quad*4+r)*PADF + 32*wv + 16*s + nl] = f2bf(hh*sg);
        }
      }
      __syncthreads();   // (3)

      // ---- gemm2: pred = a @ w1 ; dpred = 2/DH*lr*(pred - v)   (+ pack fac0)
      const ushort_t* w1tb = w1T + (size_t)bh*16384;
      f32x4 pacc[2] = {zero,zero};
      #pragma unroll
      for (int kt=0; kt<4; kt++){
        bf16x8 Af = *(const bf16x8*)&as_[nl*PADF + kt*32 + quad*8];
        #pragma unroll
        for (int s=0; s<2; s++){
          int n0 = (2*wv+s)*16;
          bf16x8 Bf = *(const bf16x8*)&w1tb[(size_t)(n0+nl)*128 + kt*32 + quad*8];
          pacc[s] = __builtin_amdgcn_mfma_f32_16x16x32_bf16(Af, Bf, pacc[s], 0,0,0);
        }
      }
      float lrv[4];
      #pragma unroll
      for (int r=0;r<4;r++) lrv[r] = lr_s[quad*4 + r];
      #pragma unroll
      for (int s=0;s<2;s++){
        #pragma unroll
        for (int r=0;r<4;r++){
          float dp = (2.0f/DHX)*lrv[r]*(pacc[s][r] - vacc[s][r]);
          dp_[(quad*4+r)*PADF + 32*wv + 16*s + nl] = f2bf(dp);
        }
      }
      if (tid < 128){
        int p = tid;
        ushort_t rowv[32];
        #pragma unroll
        for (int c=0;c<16;c++){ rowv[c] = ks[c*PADF + p]; rowv[16+c] = as_[c*PADF + p]; }
        uint4* dq = (uint4*)(fac0 + ((size_t)bt*128 + p)*32);
        const uint4* rv = (const uint4*)rowv;
        dq[0]=rv[0]; dq[1]=rv[1]; dq[2]=rv[2]; dq[3]=rv[3];
      }
      __syncthreads();   // (4)

      // ---- gemm3: da = dpred @ w1^T ; dh = da * silu'(h)
      const ushort_t* w1nb = w1n + (size_t)bh*16384;
      f32x4 dacc[2] = {zero,zero};
      #pragma unroll
      for (int kt=0; kt<4; kt++){
        bf16x8 Af = *(const bf16x8*)&dp_[nl*PADF + kt*32 + quad*8];
        #pragma unroll
        for (int s=0; s<2; s++){
          int n0 = (2*wv+s)*16;
          bf16x8 Bf = *(const bf16x8*)&w1nb[(size_t)(n0+nl)*128 + kt*32 + quad*8];
          dacc[s] = __builtin_amdgcn_mfma_f32_16x16x32_bf16(Af, Bf, dacc[s], 0,0,0);
        }
      }
      #pragma unroll
      for (int s=0;s<2;s++){
        #pragma unroll
        for (int r=0;r<4;r++)
          dh_[(quad*4+r)*PADF + 32*wv + 16*s + nl] = f2bf(dacc[s][r]*sp[s][r]);
      }
      __syncthreads();   // (5)

      if (tid < 128){
        int p = tid;
        ushort_t rowv[32];
        #pragma unroll
        for (int c=0;c<16;c++){ rowv[c] = dh_[c*PADF + p]; rowv[16+c] = dp_[c*PADF + p]; }
        uint4* dq = (uint4*)(fac1 + ((size_t)bt*128 + p)*32);
        const uint4* rv = (const uint4*)rowv;
        dq[0]=rv[0]; dq[1]=rv[1]; dq[2]=rv[2]; dq[3]=rv[3];
      }
      __syncthreads();   // (6) -- drains all global stores (vmcnt) for this chunk
      if (tid==0)
        __hip_atomic_fetch_add(&done[bh*NBAT + it], 1u,
                               __ATOMIC_RELEASE, __HIP_MEMORY_SCOPE_AGENT);
    }
  } else {
    // ================= consumer (scan3 waves, batched) =================
    int cblk = blk - 256;
    int wv = tid >> 6, lane = tid & 63;
    int task = cblk*4 + wv;
    int bh  = task & 7;
    int jb  = (task >> 3) & 7;
    int ig  = (task >> 6) & 7;
    int mat = task >> 9;
    int quad = lane >> 4, rrow = lane & 15;
    const bf16x8 fz = {0,0,0,0,0,0,0,0};

    size_t rowbase = (size_t)bh*NCX*128;
    const ushort_t* pa = fac0 + (rowbase + (size_t)(ig*16 + rrow))*32 + mat*16 + quad*8;
    const ushort_t* pb = fac1 + (rowbase + (size_t)(jb*16 + rrow))*32 + mat*16 + quad*8;
    bool act = (quad < 2);

    f32x4 m_ = zero, u_ = zero;
    size_t obase = ((size_t)(mat*BHX + bh)*NCX)*((size_t)DHX*DHX)
                 + (size_t)(ig*16 + quad*4)*DHX + (size_t)(jb*16 + rrow);
    const float* mop = momw + bh*NCX;
    const float* dep = decw + bh*NCX;

    for (int bat=0; bat<NBAT; bat++){
      int t0 = bat*BATCH;
      // wait for this batch's 32 chunks (relaxed L3 polls), then one acquire
      while (__hip_atomic_load(&done[bh*NBAT + bat], __ATOMIC_RELAXED,
                               __HIP_MEMORY_SCOPE_AGENT) < 32u)
        __builtin_amdgcn_s_sleep(8);
      __builtin_amdgcn_fence(__ATOMIC_ACQUIRE, "agent");

      bf16x8 fa0=fz, fb0=fz, fa1=fz, fb1=fz;
      if (act){
        fa0 = *(const bf16x8*)(pa + (size_t)t0*4096);
        fb0 = *(const bf16x8*)(pb + (size_t)t0*4096);
        fa1 = *(const bf16x8*)(pa + (size_t)(t0+1)*4096);
        fb1 = *(const bf16x8*)(pb + (size_t)(t0+1)*4096);
      }
      for (int t=t0; t<t0+BATCH; t+=2){
        bf16x8 na0=fz, nb0=fz, na1=fz, nb1=fz;
        if (act && (t+2 < t0+BATCH)){
          na0 = *(const bf16x8*)(pa + (size_t)(t+2)*4096);
          nb0 = *(const bf16x8*)(pb + (size_t)(t+2)*4096);
          na1 = *(const bf16x8*)(pa + (size_t)(t+3)*4096);
          nb1 = *(const bf16x8*)(pb + (size_t)(t+3)*4096);
        }
        float mo = mop[t], de = dep[t];
        f32x4 gg = __builtin_amdgcn_mfma_f32_16x16x32_bf16(fa0, fb0, zero, 0,0,0);
        float* ob = out + obase + (size_t)t*(DHX*DHX);
        #pragma unroll
        for (int r=0;r<4;r++){
          m_[r] = mo*m_[r] - gg[r];
          u_[r] = de*u_[r] + m_[r];
          ob[(size_t)r*DHX] = u_[r];
        }
        mo = mop[t+1]; de = dep[t+1];
        gg = __builtin_amdgcn_mfma_f32_16x16x32_bf16(fa1, fb1, zero, 0,0,0);
        ob += (size_t)DHX*DHX;
        #pragma unroll
        for (int r=0;r<4;r++){
          m_[r] = mo*m_[r] - gg[r];
          u_[r] = de*u_[r] + m_[r];
          ob[(size_t)r*DHX] = u_[r];
        }
        fa0=na0; fb0=nb0; fa1=na1; fb1=nb1;
      }
    }
  }
}

extern "C" void kernel_launch(void* const* d_in, const int* in_sizes, int n_in,
                              void* d_out, int out_size, void* d_ws, size_t ws_size,
                              hipStream_t stream) {
  (void)in_sizes; (void)n_in; (void)out_size; (void)ws_size;
  const float* seq   = (const float*)d_in[0];
  const float* scale = (const float*)d_in[1];
  const float* Wkv   = (const float*)d_in[2];
  const float* Wstep = (const float*)d_in[3];
  const float* Wmom  = (const float*)d_in[4];
  const float* Wdec  = (const float*)d_in[5];
  const float* w0    = (const float*)d_in[6];
  const float* w1    = (const float*)d_in[7];
  float* out = (float*)d_out;
  float* ws  = (float*)d_ws;

  // workspace layout (float units)
  ushort_t* fac0 = (ushort_t*)(ws);              // 4,194,304 ushorts
  ushort_t* fac1 = (ushort_t*)(ws + 2097152);    // 4,194,304 ushorts
  ushort_t* WkvT = (ushort_t*)(ws + 4194304);    // 524,288 ushorts
  ushort_t* w0T  = (ushort_t*)(ws + 4456448);    // 131,072 ushorts
  ushort_t* w1T  = (ushort_t*)(ws + 4521984);    // 131,072 ushorts
  ushort_t* w1n  = (ushort_t*)(ws + 4587520);    // 131,072 ushorts
  float*    momw = ws + 4653056;                 // 1,024
  float*    decw = ws + 4654080;                 // 1,024
  float*    wfsS = ws + 4655104;                 // 2,048
  float*    wfsM = ws + 4657152;                 // 2,048
  float*    wfsD = ws + 4659200;                 // 2,048
  uint_t*   done = (uint_t*)(ws + 4661248);      // 32 counters

  k_prep<<<dim3(73), dim3(256), 0, stream>>>(Wkv, w0, w1, scale, Wstep, Wmom, Wdec,
      WkvT, w0T, w1T, w1n, wfsS, wfsM, wfsD, done);
  k_pipe<<<dim3(512), dim3(256), 0, stream>>>(seq, scale, wfsS, wfsM, wfsD,
      WkvT, w0T, w1T, w1n, fac0, fac1, momw, decw, done, out);
}

// Round 8
// 445.228 us; speedup vs baseline: 1.0274x; 1.0274x over previous
//
#include <hip/hip_runtime.h>

#define DIMX 512
#define HEADSX 4
#define DHX 128
#define CHX 16
#define NCX 128
#define SX 2048
#define BX 2
#define BHX 8
#define PADX 520   // xs LDS row pad (ushorts)
#define PADF 136   // stage LDS row pad (ushorts)
#define NBAT 4     // scan batches
#define BATCH 32   // chunks per batch

typedef unsigned short ushort_t;
typedef unsigned int uint_t;
typedef short bf16x8 __attribute__((ext_vector_type(8)));
typedef float f32x4 __attribute__((ext_vector_type(4)));

__device__ __forceinline__ float sigmoidf_(float z){ return 1.0f/(1.0f + __expf(-z)); }

// fp32 -> bf16 round-to-nearest-even
__device__ __forceinline__ ushort_t f2bf(float f){
  uint_t u = __float_as_uint(f);
  return (ushort_t)((u + 0x7FFFu + ((u >> 16) & 1u)) >> 16);
}
__device__ __forceinline__ uint_t pk2(float a, float b){
  return (uint_t)f2bf(a) | ((uint_t)f2bf(b) << 16);
}

// ---------------- K-prep: bf16 weight layouts + premultiplied stat tables ----------------
__global__ __launch_bounds__(256) void k_prep(const float* __restrict__ Wkv,
    const float* __restrict__ w0, const float* __restrict__ w1,
    const float* __restrict__ scale,
    const float* __restrict__ Wstep, const float* __restrict__ Wmom,
    const float* __restrict__ Wdec,
    ushort_t* __restrict__ WkvT, ushort_t* __restrict__ w0T,
    ushort_t* __restrict__ w1T, ushort_t* __restrict__ w1n,
    float* __restrict__ wfsS, float* __restrict__ wfsM, float* __restrict__ wfsD,
    uint_t* done){
  int blk = blockIdx.x; int tid = threadIdx.x;
  if (blk < 64){
    int h = blk >> 4, kt = blk & 15;
    __shared__ ushort_t tile[256][33];   // [col][kk], +1 pad
    for (int i=tid; i<8192; i+=256){
      int kk = i >> 8, col = i & 255;    // coalesced read
      int wcol = (col < 128) ? (h*128 + col) : (384 + h*128 + col);
      float v = Wkv[(size_t)(kt*32+kk)*1024 + wcol];
      tile[col][kk] = f2bf(v);
    }
    __syncthreads();
    for (int i=tid; i<8192; i+=256){
      int col = i >> 5, kk = i & 31;     // coalesced write
      WkvT[(((size_t)h*16 + kt)*256 + col)*32 + kk] = tile[col][kk];
    }
  } else if (blk < 72){
    int bh = blk - 64;
    size_t base = (size_t)bh*16384;
    for (int i=tid; i<16384; i+=256){
      int r = i >> 7, c = i & 127;
      w0T[base + i] = f2bf(w0[base + (size_t)c*128 + r]);
      w1T[base + i] = f2bf(w1[base + (size_t)c*128 + r]);
      w1n[base + i] = f2bf(w1[base + i]);
    }
  } else {
    for (int i=tid; i<2048; i+=256){
      int d = i & 511, h = i >> 9;
      float sc = scale[d];
      wfsS[i] = sc * Wstep[d*4 + h];
      wfsM[i] = sc * Wmom [d*4 + h];
      wfsD[i] = sc * Wdec [d*4 + h];
    }
    // reset pipeline counters
    if (tid < BHX*NBAT)
      __hip_atomic_store(&done[tid], 0u, __ATOMIC_RELAXED, __HIP_MEMORY_SCOPE_AGENT);
  }
}

// ---------------- K-pipe: producer/consumer pipeline (XCD-aligned both roles) ----------------
// 512 blocks x 256 threads, __launch_bounds__(256,2): 34KB LDS, 128 VGPR ->
// 2 blocks/CU -> all 512 co-resident (no spin deadlock).
// XCD id = blk%8 (round-robin). Producers (blk<256): bh = blk&7 -> XCD bh.
// Consumers (blk>=256): bh = (blk-256)&7 -> ALSO XCD bh. So each XCD owns one
// bh end-to-end: fac written to its L2, read back from the same L2/L3, and the
// two adjacent jb 64B half-lines of each out 128B line are written by blocks on
// the SAME XCD -> L2 merges -> full-line writeback (no RMW; R7's 1.5TB/s bug).
// Consumer block waves share bh: q=(cblk>>3)*4+wv -> (jb,ig,mat); 32 blocks x
// 4 waves = 128 tasks per bh.
__global__ __launch_bounds__(256, 2) void k_pipe(const float* __restrict__ seq,
    const float* __restrict__ scale,
    const float* __restrict__ wfsS, const float* __restrict__ wfsM,
    const float* __restrict__ wfsD,
    const ushort_t* __restrict__ WkvT, const ushort_t* __restrict__ w0T,
    const ushort_t* __restrict__ w1T, const ushort_t* __restrict__ w1n,
    ushort_t* __restrict__ fac0, ushort_t* __restrict__ fac1,
    float* __restrict__ momw, float* __restrict__ decw,
    uint_t* done, float* __restrict__ out){
  __shared__ __align__(16) ushort_t xs[16*PADX];
  __shared__ __align__(16) ushort_t ks[16*PADF];
  __shared__ __align__(16) ushort_t as_[16*PADF];
  __shared__ __align__(16) ushort_t dp_[16*PADF];
  __shared__ __align__(16) ushort_t dh_[16*PADF];
  __shared__ float lr_s[16];
  __shared__ float red_m[4], red_d[4];
  int blk = blockIdx.x;
  int tid = threadIdx.x;
  const f32x4 zero = {0.f,0.f,0.f,0.f};

  if (blk < 256){
    // ================= producer =================
    int bh = blk & 7, g = blk >> 3;
    int b = bh >> 2, h = bh & 3;
    int wv = tid >> 6, lane = tid & 63;
    int quad = lane >> 4, nl = lane & 15;

    for (int it=0; it<4; it++){
      int t = g + 32*it;
      int bt = bh*NCX + t;

      // ---- phase 0: stats + normalized bf16 x into LDS
      {
        int c = tid >> 4, sl = tid & 15;
        const float4* sr = (const float4*)(seq + ((size_t)(b*SX + t*CHX) + c)*DIMX);
        const float4* scl = (const float4*)scale;
        const float4* wS = (const float4*)(wfsS + h*512);
        const float4* wM = (const float4*)(wfsM + h*512);
        const float4* wD = (const float4*)(wfsD + h*512);
        float4 q[8];
        #pragma unroll
        for (int jj=0; jj<8; jj++) q[jj] = sr[sl + 16*jj];
        float ss=0.f, lp=0.f, pm=0.f, pd=0.f;
        #pragma unroll
        for (int jj=0; jj<8; jj++){
          float4 a = q[jj];
          float4 s4 = wS[sl+16*jj], m4 = wM[sl+16*jj], d4 = wD[sl+16*jj];
          ss += a.x*a.x + a.y*a.y + a.z*a.z + a.w*a.w;
          lp += a.x*s4.x + a.y*s4.y + a.z*s4.z + a.w*s4.w;
          pm += a.x*m4.x + a.y*m4.y + a.z*m4.z + a.w*m4.w;
          pd += a.x*d4.x + a.y*d4.y + a.z*d4.z + a.w*d4.w;
        }
        #pragma unroll
        for (int mk=1; mk<16; mk<<=1){
          ss += __shfl_xor(ss,mk,64); lp += __shfl_xor(lp,mk,64);
          pm += __shfl_xor(pm,mk,64); pd += __shfl_xor(pd,mk,64);
        }
        float rs = 1.0f / sqrtf(ss*(1.0f/DIMX) + 1e-6f);
        if (sl==0) lr_s[c] = 0.01f * sigmoidf_(rs*lp);
        float pmr = rs*pm, pdr = rs*pd;
        #pragma unroll
        for (int mk=16; mk<64; mk<<=1){ pmr += __shfl_xor(pmr,mk,64); pdr += __shfl_xor(pdr,mk,64); }
        if (lane==0){ red_m[wv]=pmr; red_d[wv]=pdr; }
        #pragma unroll
        for (int jj=0; jj<8; jj++){
          float4 s4 = scl[sl+16*jj];
          uint2 u;
          u.x = pk2(q[jj].x*rs*s4.x, q[jj].y*rs*s4.y);
          u.y = pk2(q[jj].z*rs*s4.z, q[jj].w*rs*s4.w);
          *(uint2*)&xs[c*PADX + (sl+16*jj)*4] = u;
        }
      }
      __syncthreads();   // (1)
      if (tid==0){
        momw[bt] = sigmoidf_((red_m[0]+red_m[1]+red_m[2]+red_m[3])*(1.0f/CHX));
        decw[bt] = 1.0f - sigmoidf_((red_d[0]+red_d[1]+red_d[2]+red_d[3])*(1.0f/CHX));
      }

      // ---- KV gemm: M=16, N=256 (k|v), K=512
      f32x4 kacc[2] = {zero,zero};
      f32x4 vacc[2] = {zero,zero};
      const ushort_t* wkvh = WkvT + (size_t)h*16*256*32;
      for (int kt=0; kt<16; kt++){
        bf16x8 Af = *(const bf16x8*)&xs[nl*PADX + kt*32 + quad*8];
        #pragma unroll
        for (int s=0; s<2; s++){
          int ktile = 2*wv + s;
          bf16x8 Bk = *(const bf16x8*)&wkvh[((size_t)kt*256 + (ktile*16+nl))*32 + quad*8];
          kacc[s] = __builtin_amdgcn_mfma_f32_16x16x32_bf16(Af, Bk, kacc[s], 0,0,0);
          int vtile = 8 + 2*wv + s;
          bf16x8 Bv = *(const bf16x8*)&wkvh[((size_t)kt*256 + (vtile*16+nl))*32 + quad*8];
          vacc[s] = __builtin_amdgcn_mfma_f32_16x16x32_bf16(Af, Bv, vacc[s], 0,0,0);
        }
      }
      #pragma unroll
      for (int s=0;s<2;s++){
        #pragma unroll
        for (int r=0;r<4;r++)
          ks[(quad*4+r)*PADF + 32*wv + 16*s + nl] = f2bf(kacc[s][r]);
      }
      __syncthreads();   // (2)

      // ---- gemm1: h = k @ w0
      const ushort_t* w0b = w0T + (size_t)bh*16384;
      f32x4 hacc[2] = {zero,zero};
      #pragma unroll
      for (int kt=0; kt<4; kt++){
        bf16x8 Af = *(const bf16x8*)&ks[nl*PADF + kt*32 + quad*8];
        #pragma unroll
        for (int s=0; s<2; s++){
          int n0 = (2*wv+s)*16;
          bf16x8 Bf = *(const bf16x8*)&w0b[(size_t)(n0+nl)*128 + kt*32 + quad*8];
          hacc[s] = __builtin_amdgcn_mfma_f32_16x16x32_bf16(Af, Bf, hacc[s], 0,0,0);
        }
      }
      float sp[2][4];
      #pragma unroll
      for (int s=0;s<2;s++){
        #pragma unroll
        for (int r=0;r<4;r++){
          float hh = hacc[s][r];
          float sg = sigmoidf_(hh);
          sp[s][r] = sg*(1.0f + hh*(1.0f-sg));
          as_[(quad*4+r)*PADF + 32*wv + 16*s + nl] = f2bf(hh*sg);
        }
      }
      __syncthreads();   // (3)

      // ---- gemm2: pred = a @ w1 ; dpred = 2/DH*lr*(pred - v)   (+ pack fac0)
      const ushort_t* w1tb = w1T + (size_t)bh*16384;
      f32x4 pacc[2] = {zero,zero};
      #pragma unroll
      for (int kt=0; kt<4; kt++){
        bf16x8 Af = *(const bf16x8*)&as_[nl*PADF + kt*32 + quad*8];
        #pragma unroll
        for (int s=0; s<2; s++){
          int n0 = (2*wv+s)*16;
          bf16x8 Bf = *(const bf16x8*)&w1tb[(size_t)(n0+nl)*128 + kt*32 + quad*8];
          pacc[s] = __builtin_amdgcn_mfma_f32_16x16x32_bf16(Af, Bf, pacc[s], 0,0,0);
        }
      }
      float lrv[4];
      #pragma unroll
      for (int r=0;r<4;r++) lrv[r] = lr_s[quad*4 + r];
      #pragma unroll
      for (int s=0;s<2;s++){
        #pragma unroll
        for (int r=0;r<4;r++){
          float dp = (2.0f/DHX)*lrv[r]*(pacc[s][r] - vacc[s][r]);
          dp_[(quad*4+r)*PADF + 32*wv + 16*s + nl] = f2bf(dp);
        }
      }
      if (tid < 128){
        int p = tid;
        ushort_t rowv[32];
        #pragma unroll
        for (int c=0;c<16;c++){ rowv[c] = ks[c*PADF + p]; rowv[16+c] = as_[c*PADF + p]; }
        uint4* dq = (uint4*)(fac0 + ((size_t)bt*128 + p)*32);
        const uint4* rv = (const uint4*)rowv;
        dq[0]=rv[0]; dq[1]=rv[1]; dq[2]=rv[2]; dq[3]=rv[3];
      }
      __syncthreads();   // (4)

      // ---- gemm3: da = dpred @ w1^T ; dh = da * silu'(h)
      const ushort_t* w1nb = w1n + (size_t)bh*16384;
      f32x4 dacc[2] = {zero,zero};
      #pragma unroll
      for (int kt=0; kt<4; kt++){
        bf16x8 Af = *(const bf16x8*)&dp_[nl*PADF + kt*32 + quad*8];
        #pragma unroll
        for (int s=0; s<2; s++){
          int n0 = (2*wv+s)*16;
          bf16x8 Bf = *(const bf16x8*)&w1nb[(size_t)(n0+nl)*128 + kt*32 + quad*8];
          dacc[s] = __builtin_amdgcn_mfma_f32_16x16x32_bf16(Af, Bf, dacc[s], 0,0,0);
        }
      }
      #pragma unroll
      for (int s=0;s<2;s++){
        #pragma unroll
        for (int r=0;r<4;r++)
          dh_[(quad*4+r)*PADF + 32*wv + 16*s + nl] = f2bf(dacc[s][r]*sp[s][r]);
      }
      __syncthreads();   // (5)

      if (tid < 128){
        int p = tid;
        ushort_t rowv[32];
        #pragma unroll
        for (int c=0;c<16;c++){ rowv[c] = dh_[c*PADF + p]; rowv[16+c] = dp_[c*PADF + p]; }
        uint4* dq = (uint4*)(fac1 + ((size_t)bt*128 + p)*32);
        const uint4* rv = (const uint4*)rowv;
        dq[0]=rv[0]; dq[1]=rv[1]; dq[2]=rv[2]; dq[3]=rv[3];
      }
      __syncthreads();   // (6) -- drains all global stores for this chunk
      if (tid==0)
        __hip_atomic_fetch_add(&done[bh*NBAT + it], 1u,
                               __ATOMIC_RELEASE, __HIP_MEMORY_SCOPE_AGENT);
    }
  } else {
    // ================= consumer (scan waves, batched; bh shared per block) =================
    int cblk = blk - 256;
    int wv = tid >> 6, lane = tid & 63;
    int bh  = cblk & 7;                 // XCD = blk%8 = cblk%8 = bh (matches producers)
    int q   = (cblk >> 3)*4 + wv;       // 0..127 task within bh
    int jb  = q & 7;
    int ig  = (q >> 3) & 7;
    int mat = q >> 6;
    int quad = lane >> 4, rrow = lane & 15;
    const bf16x8 fz = {0,0,0,0,0,0,0,0};

    size_t rowbase = (size_t)bh*NCX*128;
    const ushort_t* pa = fac0 + (rowbase + (size_t)(ig*16 + rrow))*32 + mat*16 + quad*8;
    const ushort_t* pb = fac1 + (rowbase + (size_t)(jb*16 + rrow))*32 + mat*16 + quad*8;
    bool act = (quad < 2);

    f32x4 m_ = zero, u_ = zero;
    size_t obase = ((size_t)(mat*BHX + bh)*NCX)*((size_t)DHX*DHX)
                 + (size_t)(ig*16 + quad*4)*DHX + (size_t)(jb*16 + rrow);
    const float* mop = momw + bh*NCX;
    const float* dep = decw + bh*NCX;

    for (int bat=0; bat<NBAT; bat++){
      int t0 = bat*BATCH;
      // wait for this batch's 32 chunks (relaxed polls), then one acquire fence
      while (__hip_atomic_load(&done[bh*NBAT + bat], __ATOMIC_RELAXED,
                               __HIP_MEMORY_SCOPE_AGENT) < 32u)
        __builtin_amdgcn_s_sleep(32);
      __builtin_amdgcn_fence(__ATOMIC_ACQUIRE, "agent");

      bf16x8 fa0=fz, fb0=fz, fa1=fz, fb1=fz;
      if (act){
        fa0 = *(const bf16x8*)(pa + (size_t)t0*4096);
        fb0 = *(const bf16x8*)(pb + (size_t)t0*4096);
        fa1 = *(const bf16x8*)(pa + (size_t)(t0+1)*4096);
        fb1 = *(const bf16x8*)(pb + (size_t)(t0+1)*4096);
      }
      for (int t=t0; t<t0+BATCH; t+=2){
        bf16x8 na0=fz, nb0=fz, na1=fz, nb1=fz;
        if (act && (t+2 < t0+BATCH)){
          na0 = *(const bf16x8*)(pa + (size_t)(t+2)*4096);
          nb0 = *(const bf16x8*)(pb + (size_t)(t+2)*4096);
          na1 = *(const bf16x8*)(pa + (size_t)(t+3)*4096);
          nb1 = *(const bf16x8*)(pb + (size_t)(t+3)*4096);
        }
        float mo = mop[t], de = dep[t];
        f32x4 gg = __builtin_amdgcn_mfma_f32_16x16x32_bf16(fa0, fb0, zero, 0,0,0);
        float* ob = out + obase + (size_t)t*(DHX*DHX);
        #pragma unroll
        for (int r=0;r<4;r++){
          m_[r] = mo*m_[r] - gg[r];
          u_[r] = de*u_[r] + m_[r];
          ob[(size_t)r*DHX] = u_[r];
        }
        mo = mop[t+1]; de = dep[t+1];
        gg = __builtin_amdgcn_mfma_f32_16x16x32_bf16(fa1, fb1, zero, 0,0,0);
        ob += (size_t)DHX*DHX;
        #pragma unroll
        for (int r=0;r<4;r++){
          m_[r] = mo*m_[r] - gg[r];
          u_[r] = de*u_[r] + m_[r];
          ob[(size_t)r*DHX] = u_[r];
        }
        fa0=na0; fb0=nb0; fa1=na1; fb1=nb1;
      }
    }
  }
}

extern "C" void kernel_launch(void* const* d_in, const int* in_sizes, int n_in,
                              void* d_out, int out_size, void* d_ws, size_t ws_size,
                              hipStream_t stream) {
  (void)in_sizes; (void)n_in; (void)out_size; (void)ws_size;
  const float* seq   = (const float*)d_in[0];
  const float* scale = (const float*)d_in[1];
  const float* Wkv   = (const float*)d_in[2];
  const float* Wstep = (const float*)d_in[3];
  const float* Wmom  = (const float*)d_in[4];
  const float* Wdec  = (const float*)d_in[5];
  const float* w0    = (const float*)d_in[6];
  const float* w1    = (const float*)d_in[7];
  float* out = (float*)d_out;
  float* ws  = (float*)d_ws;

  // workspace layout (float units)
  ushort_t* fac0 = (ushort_t*)(ws);              // 4,194,304 ushorts
  ushort_t* fac1 = (ushort_t*)(ws + 2097152);    // 4,194,304 ushorts
  ushort_t* WkvT = (ushort_t*)(ws + 4194304);    // 524,288 ushorts
  ushort_t* w0T  = (ushort_t*)(ws + 4456448);    // 131,072 ushorts
  ushort_t* w1T  = (ushort_t*)(ws + 4521984);    // 131,072 ushorts
  ushort_t* w1n  = (ushort_t*)(ws + 4587520);    // 131,072 ushorts
  float*    momw = ws + 4653056;                 // 1,024
  float*    decw = ws + 4654080;                 // 1,024
  float*    wfsS = ws + 4655104;                 // 2,048
  float*    wfsM = ws + 4657152;                 // 2,048
  float*    wfsD = ws + 4659200;                 // 2,048
  uint_t*   done = (uint_t*)(ws + 4661248);      // 32 counters

  k_prep<<<dim3(73), dim3(256), 0, stream>>>(Wkv, w0, w1, scale, Wstep, Wmom, Wdec,
      WkvT, w0T, w1T, w1n, wfsS, wfsM, wfsD, done);
  k_pipe<<<dim3(512), dim3(256), 0, stream>>>(seq, scale, wfsS, wfsM, wfsD,
      WkvT, w0T, w1T, w1n, fac0, fac1, momw, decw, done, out);
}

// Round 9
// 304.381 us; speedup vs baseline: 1.5028x; 1.4627x over previous
//
#include <hip/hip_runtime.h>

#define DIMX 512
#define HEADSX 4
#define DHX 128
#define CHX 16
#define NCX 128
#define SX 2048
#define BX 2
#define BHX 8
#define PADX 520   // xs LDS row pad (ushorts)
#define PADF 136   // stage LDS row pad (ushorts)
#define NBAT 4     // scan batches
#define BATCH 32   // chunks per batch

typedef unsigned short ushort_t;
typedef unsigned int uint_t;
typedef short bf16x8 __attribute__((ext_vector_type(8)));
typedef float f32x4 __attribute__((ext_vector_type(4)));

__device__ __forceinline__ float sigmoidf_(float z){ return 1.0f/(1.0f + __expf(-z)); }

// fp32 -> bf16 round-to-nearest-even
__device__ __forceinline__ ushort_t f2bf(float f){
  uint_t u = __float_as_uint(f);
  return (ushort_t)((u + 0x7FFFu + ((u >> 16) & 1u)) >> 16);
}
__device__ __forceinline__ uint_t pk2(float a, float b){
  return (uint_t)f2bf(a) | ((uint_t)f2bf(b) << 16);
}

// ---------------- K-prep: bf16 weight layouts + premultiplied stat tables ----------------
__global__ __launch_bounds__(256) void k_prep(const float* __restrict__ Wkv,
    const float* __restrict__ w0, const float* __restrict__ w1,
    const float* __restrict__ scale,
    const float* __restrict__ Wstep, const float* __restrict__ Wmom,
    const float* __restrict__ Wdec,
    ushort_t* __restrict__ WkvT, ushort_t* __restrict__ w0T,
    ushort_t* __restrict__ w1T, ushort_t* __restrict__ w1n,
    float* __restrict__ wfsS, float* __restrict__ wfsM, float* __restrict__ wfsD,
    uint_t* done){
  int blk = blockIdx.x; int tid = threadIdx.x;
  if (blk < 64){
    int h = blk >> 4, kt = blk & 15;
    __shared__ ushort_t tile[256][33];   // [col][kk], +1 pad
    for (int i=tid; i<8192; i+=256){
      int kk = i >> 8, col = i & 255;    // coalesced read
      int wcol = (col < 128) ? (h*128 + col) : (384 + h*128 + col);
      float v = Wkv[(size_t)(kt*32+kk)*1024 + wcol];
      tile[col][kk] = f2bf(v);
    }
    __syncthreads();
    for (int i=tid; i<8192; i+=256){
      int col = i >> 5, kk = i & 31;     // coalesced write
      WkvT[(((size_t)h*16 + kt)*256 + col)*32 + kk] = tile[col][kk];
    }
  } else if (blk < 72){
    int bh = blk - 64;
    size_t base = (size_t)bh*16384;
    for (int i=tid; i<16384; i+=256){
      int r = i >> 7, c = i & 127;
      w0T[base + i] = f2bf(w0[base + (size_t)c*128 + r]);
      w1T[base + i] = f2bf(w1[base + (size_t)c*128 + r]);
      w1n[base + i] = f2bf(w1[base + i]);
    }
  } else {
    for (int i=tid; i<2048; i+=256){
      int d = i & 511, h = i >> 9;
      float sc = scale[d];
      wfsS[i] = sc * Wstep[d*4 + h];
      wfsM[i] = sc * Wmom [d*4 + h];
      wfsD[i] = sc * Wdec [d*4 + h];
    }
    // reset pipeline counters
    if (tid < BHX*NBAT)
      __hip_atomic_store(&done[tid], 0u, __ATOMIC_RELAXED, __HIP_MEMORY_SCOPE_AGENT);
  }
}

// ---------------- K-pipe2: 1024 one-chunk producers + 256 consumer blocks ----------------
// Blocks 0..1023: EXACT R3 fused2 body, one chunk each (bh=blk&7, t=blk>>3;
//   dispatch order == batch order). Ends: barrier (drains stores) + release
//   atomicAdd on done[bh][t>>5].
// Blocks 1024..1279: consumers, 4 waves each. Block c: bh=c&7, q=c>>3 ->
//   mat=q>>4, ig=(q>>1)&7, jbH=q&1; wave w: jb=jbH*4+w. Adjacent jb (the two
//   64B halves of each out 128B line) are waves of the SAME block -> same XCD,
//   near-simultaneous -> L2 merges full lines. Each wave = exact scan3 task,
//   processing 4 batches of 32 chunks behind the done counters.
// Producers never wait -> deadlock-free; worst case is serial (== R3).
__global__ __launch_bounds__(256, 2) void k_pipe2(const float* __restrict__ seq,
    const float* __restrict__ scale,
    const float* __restrict__ wfsS, const float* __restrict__ wfsM,
    const float* __restrict__ wfsD,
    const ushort_t* __restrict__ WkvT, const ushort_t* __restrict__ w0T,
    const ushort_t* __restrict__ w1T, const ushort_t* __restrict__ w1n,
    ushort_t* __restrict__ fac0, ushort_t* __restrict__ fac1,
    float* __restrict__ momw, float* __restrict__ decw,
    uint_t* done, float* __restrict__ out){
  __shared__ __align__(16) ushort_t xs[16*PADX];
  __shared__ __align__(16) ushort_t ks[16*PADF];
  __shared__ __align__(16) ushort_t as_[16*PADF];
  __shared__ __align__(16) ushort_t dp_[16*PADF];
  __shared__ __align__(16) ushort_t dh_[16*PADF];
  __shared__ float lr_s[16];
  __shared__ float red_m[4], red_d[4];
  int blk = blockIdx.x;
  int tid = threadIdx.x;
  const f32x4 zero = {0.f,0.f,0.f,0.f};

  if (blk < 1024){
    // ================= producer: one chunk (R3 fused2 body) =================
    int bh = blk & 7, t = blk >> 3;
    int b = bh >> 2, h = bh & 3;
    int bt = bh*NCX + t;
    int wv = tid >> 6, lane = tid & 63;
    int quad = lane >> 4, nl = lane & 15;

    // ---- phase 0: stats + normalized bf16 x into LDS
    {
      int c = tid >> 4, sl = tid & 15;
      const float4* sr = (const float4*)(seq + ((size_t)(b*SX + t*CHX) + c)*DIMX);
      const float4* scl = (const float4*)scale;
      const float4* wS = (const float4*)(wfsS + h*512);
      const float4* wM = (const float4*)(wfsM + h*512);
      const float4* wD = (const float4*)(wfsD + h*512);
      float4 q[8];
      #pragma unroll
      for (int jj=0; jj<8; jj++) q[jj] = sr[sl + 16*jj];
      float ss=0.f, lp=0.f, pm=0.f, pd=0.f;
      #pragma unroll
      for (int jj=0; jj<8; jj++){
        float4 a = q[jj];
        float4 s4 = wS[sl+16*jj], m4 = wM[sl+16*jj], d4 = wD[sl+16*jj];
        ss += a.x*a.x + a.y*a.y + a.z*a.z + a.w*a.w;
        lp += a.x*s4.x + a.y*s4.y + a.z*s4.z + a.w*s4.w;
        pm += a.x*m4.x + a.y*m4.y + a.z*m4.z + a.w*m4.w;
        pd += a.x*d4.x + a.y*d4.y + a.z*d4.z + a.w*d4.w;
      }
      #pragma unroll
      for (int mk=1; mk<16; mk<<=1){
        ss += __shfl_xor(ss,mk,64); lp += __shfl_xor(lp,mk,64);
        pm += __shfl_xor(pm,mk,64); pd += __shfl_xor(pd,mk,64);
      }
      float rs = 1.0f / sqrtf(ss*(1.0f/DIMX) + 1e-6f);
      if (sl==0) lr_s[c] = 0.01f * sigmoidf_(rs*lp);
      float pmr = rs*pm, pdr = rs*pd;
      #pragma unroll
      for (int mk=16; mk<64; mk<<=1){ pmr += __shfl_xor(pmr,mk,64); pdr += __shfl_xor(pdr,mk,64); }
      if (lane==0){ red_m[wv]=pmr; red_d[wv]=pdr; }
      #pragma unroll
      for (int jj=0; jj<8; jj++){
        float4 s4 = scl[sl+16*jj];
        uint2 u;
        u.x = pk2(q[jj].x*rs*s4.x, q[jj].y*rs*s4.y);
        u.y = pk2(q[jj].z*rs*s4.z, q[jj].w*rs*s4.w);
        *(uint2*)&xs[c*PADX + (sl+16*jj)*4] = u;
      }
    }
    __syncthreads();   // (1)
    if (tid==0){
      momw[bt] = sigmoidf_((red_m[0]+red_m[1]+red_m[2]+red_m[3])*(1.0f/CHX));
      decw[bt] = 1.0f - sigmoidf_((red_d[0]+red_d[1]+red_d[2]+red_d[3])*(1.0f/CHX));
    }

    // ---- KV gemm: M=16, N=256 (k|v), K=512
    f32x4 kacc[2] = {zero,zero};
    f32x4 vacc[2] = {zero,zero};
    const ushort_t* wkvh = WkvT + (size_t)h*16*256*32;
    for (int kt=0; kt<16; kt++){
      bf16x8 Af = *(const bf16x8*)&xs[nl*PADX + kt*32 + quad*8];
      #pragma unroll
      for (int s=0; s<2; s++){
        int ktile = 2*wv + s;
        bf16x8 Bk = *(const bf16x8*)&wkvh[((size_t)kt*256 + (ktile*16+nl))*32 + quad*8];
        kacc[s] = __builtin_amdgcn_mfma_f32_16x16x32_bf16(Af, Bk, kacc[s], 0,0,0);
        int vtile = 8 + 2*wv + s;
        bf16x8 Bv = *(const bf16x8*)&wkvh[((size_t)kt*256 + (vtile*16+nl))*32 + quad*8];
        vacc[s] = __builtin_amdgcn_mfma_f32_16x16x32_bf16(Af, Bv, vacc[s], 0,0,0);
      }
    }
    #pragma unroll
    for (int s=0;s<2;s++){
      #pragma unroll
      for (int r=0;r<4;r++)
        ks[(quad*4+r)*PADF + 32*wv + 16*s + nl] = f2bf(kacc[s][r]);
    }
    __syncthreads();   // (2)

    // ---- gemm1: h = k @ w0
    const ushort_t* w0b = w0T + (size_t)bh*16384;
    f32x4 hacc[2] = {zero,zero};
    #pragma unroll
    for (int kt=0; kt<4; kt++){
      bf16x8 Af = *(const bf16x8*)&ks[nl*PADF + kt*32 + quad*8];
      #pragma unroll
      for (int s=0; s<2; s++){
        int n0 = (2*wv+s)*16;
        bf16x8 Bf = *(const bf16x8*)&w0b[(size_t)(n0+nl)*128 + kt*32 + quad*8];
        hacc[s] = __builtin_amdgcn_mfma_f32_16x16x32_bf16(Af, Bf, hacc[s], 0,0,0);
      }
    }
    float sp[2][4];
    #pragma unroll
    for (int s=0;s<2;s++){
      #pragma unroll
      for (int r=0;r<4;r++){
        float hh = hacc[s][r];
        float sg = sigmoidf_(hh);
        sp[s][r] = sg*(1.0f + hh*(1.0f-sg));
        as_[(quad*4+r)*PADF + 32*wv + 16*s + nl] = f2bf(hh*sg);
      }
    }
    __syncthreads();   // (3)

    // ---- gemm2: pred = a @ w1 ; dpred = 2/DH*lr*(pred - v)
    const ushort_t* w1tb = w1T + (size_t)bh*16384;
    f32x4 pacc[2] = {zero,zero};
    #pragma unroll
    for (int kt=0; kt<4; kt++){
      bf16x8 Af = *(const bf16x8*)&as_[nl*PADF + kt*32 + quad*8];
      #pragma unroll
      for (int s=0; s<2; s++){
        int n0 = (2*wv+s)*16;
        bf16x8 Bf = *(const bf16x8*)&w1tb[(size_t)(n0+nl)*128 + kt*32 + quad*8];
        pacc[s] = __builtin_amdgcn_mfma_f32_16x16x32_bf16(Af, Bf, pacc[s], 0,0,0);
      }
    }
    float lrv[4];
    #pragma unroll
    for (int r=0;r<4;r++) lrv[r] = lr_s[quad*4 + r];
    #pragma unroll
    for (int s=0;s<2;s++){
      #pragma unroll
      for (int r=0;r<4;r++){
        float dp = (2.0f/DHX)*lrv[r]*(pacc[s][r] - vacc[s][r]);
        dp_[(quad*4+r)*PADF + 32*wv + 16*s + nl] = f2bf(dp);
      }
    }
    __syncthreads();   // (4)

    // ---- gemm3: da = dpred @ w1^T ; dh = da * silu'(h)
    const ushort_t* w1nb = w1n + (size_t)bh*16384;
    f32x4 dacc[2] = {zero,zero};
    #pragma unroll
    for (int kt=0; kt<4; kt++){
      bf16x8 Af = *(const bf16x8*)&dp_[nl*PADF + kt*32 + quad*8];
      #pragma unroll
      for (int s=0; s<2; s++){
        int n0 = (2*wv+s)*16;
        bf16x8 Bf = *(const bf16x8*)&w1nb[(size_t)(n0+nl)*128 + kt*32 + quad*8];
        dacc[s] = __builtin_amdgcn_mfma_f32_16x16x32_bf16(Af, Bf, dacc[s], 0,0,0);
      }
    }
    #pragma unroll
    for (int s=0;s<2;s++){
      #pragma unroll
      for (int r=0;r<4;r++)
        dh_[(quad*4+r)*PADF + 32*wv + 16*s + nl] = f2bf(dacc[s][r]*sp[s][r]);
    }
    __syncthreads();   // (5)

    // ---- pack: fac0[p] = {k | a}, fac1[p] = {dh | dp}
    {
      int p = tid & 127, which = tid >> 7;
      const ushort_t* s0 = which ? dh_ : ks;
      const ushort_t* s1 = which ? dp_ : as_;
      ushort_t rowv[32];
      #pragma unroll
      for (int c=0;c<16;c++){ rowv[c] = s0[c*PADF + p]; rowv[16+c] = s1[c*PADF + p]; }
      ushort_t* dst = (which ? fac1 : fac0) + ((size_t)bt*128 + p)*32;
      const uint4* rv = (const uint4*)rowv;
      uint4* dq = (uint4*)dst;
      dq[0]=rv[0]; dq[1]=rv[1]; dq[2]=rv[2]; dq[3]=rv[3];
    }
    __syncthreads();   // (6) -- drains all global stores for this chunk
    if (tid==0)
      __hip_atomic_fetch_add(&done[bh*NBAT + (t>>5)], 1u,
                             __ATOMIC_RELEASE, __HIP_MEMORY_SCOPE_AGENT);
  } else {
    // ================= consumer: 4 scan waves, adjacent-jb in same block =================
    int c = blk - 1024;          // 0..255
    int bh  = c & 7;
    int q   = c >> 3;            // 0..31
    int mat = q >> 4;            // 0..1
    int ig  = (q >> 1) & 7;      // 0..7
    int jbH = q & 1;             // 0..1
    int wv = tid >> 6, lane = tid & 63;
    int jb = jbH*4 + wv;         // 0..7
    int quad = lane >> 4, rrow = lane & 15;
    const bf16x8 fz = {0,0,0,0,0,0,0,0};

    size_t rowbase = (size_t)bh*NCX*128;
    const ushort_t* pa = fac0 + (rowbase + (size_t)(ig*16 + rrow))*32 + mat*16 + quad*8;
    const ushort_t* pb = fac1 + (rowbase + (size_t)(jb*16 + rrow))*32 + mat*16 + quad*8;
    bool act = (quad < 2);

    f32x4 m_ = zero, u_ = zero;
    size_t obase = ((size_t)(mat*BHX + bh)*NCX)*((size_t)DHX*DHX)
                 + (size_t)(ig*16 + quad*4)*DHX + (size_t)(jb*16 + rrow);
    const float* mop = momw + bh*NCX;
    const float* dep = decw + bh*NCX;

    for (int bat=0; bat<NBAT; bat++){
      int t0 = bat*BATCH;
      while (__hip_atomic_load(&done[bh*NBAT + bat], __ATOMIC_RELAXED,
                               __HIP_MEMORY_SCOPE_AGENT) < 32u)
        __builtin_amdgcn_s_sleep(32);
      __builtin_amdgcn_fence(__ATOMIC_ACQUIRE, "agent");

      bf16x8 fa0=fz, fb0=fz, fa1=fz, fb1=fz;
      if (act){
        fa0 = *(const bf16x8*)(pa + (size_t)t0*4096);
        fb0 = *(const bf16x8*)(pb + (size_t)t0*4096);
        fa1 = *(const bf16x8*)(pa + (size_t)(t0+1)*4096);
        fb1 = *(const bf16x8*)(pb + (size_t)(t0+1)*4096);
      }
      for (int t=t0; t<t0+BATCH; t+=2){
        bf16x8 na0=fz, nb0=fz, na1=fz, nb1=fz;
        if (act && (t+2 < t0+BATCH)){
          na0 = *(const bf16x8*)(pa + (size_t)(t+2)*4096);
          nb0 = *(const bf16x8*)(pb + (size_t)(t+2)*4096);
          na1 = *(const bf16x8*)(pa + (size_t)(t+3)*4096);
          nb1 = *(const bf16x8*)(pb + (size_t)(t+3)*4096);
        }
        float mo = mop[t], de = dep[t];
        f32x4 gg = __builtin_amdgcn_mfma_f32_16x16x32_bf16(fa0, fb0, zero, 0,0,0);
        float* ob = out + obase + (size_t)t*(DHX*DHX);
        #pragma unroll
        for (int r=0;r<4;r++){
          m_[r] = mo*m_[r] - gg[r];
          u_[r] = de*u_[r] + m_[r];
          ob[(size_t)r*DHX] = u_[r];
        }
        mo = mop[t+1]; de = dep[t+1];
        gg = __builtin_amdgcn_mfma_f32_16x16x32_bf16(fa1, fb1, zero, 0,0,0);
        ob += (size_t)DHX*DHX;
        #pragma unroll
        for (int r=0;r<4;r++){
          m_[r] = mo*m_[r] - gg[r];
          u_[r] = de*u_[r] + m_[r];
          ob[(size_t)r*DHX] = u_[r];
        }
        fa0=na0; fb0=nb0; fa1=na1; fb1=nb1;
      }
    }
  }
}

extern "C" void kernel_launch(void* const* d_in, const int* in_sizes, int n_in,
                              void* d_out, int out_size, void* d_ws, size_t ws_size,
                              hipStream_t stream) {
  (void)in_sizes; (void)n_in; (void)out_size; (void)ws_size;
  const float* seq   = (const float*)d_in[0];
  const float* scale = (const float*)d_in[1];
  const float* Wkv   = (const float*)d_in[2];
  const float* Wstep = (const float*)d_in[3];
  const float* Wmom  = (const float*)d_in[4];
  const float* Wdec  = (const float*)d_in[5];
  const float* w0    = (const float*)d_in[6];
  const float* w1    = (const float*)d_in[7];
  float* out = (float*)d_out;
  float* ws  = (float*)d_ws;

  // workspace layout (float units)
  ushort_t* fac0 = (ushort_t*)(ws);              // 4,194,304 ushorts
  ushort_t* fac1 = (ushort_t*)(ws + 2097152);    // 4,194,304 ushorts
  ushort_t* WkvT = (ushort_t*)(ws + 4194304);    // 524,288 ushorts
  ushort_t* w0T  = (ushort_t*)(ws + 4456448);    // 131,072 ushorts
  ushort_t* w1T  = (ushort_t*)(ws + 4521984);    // 131,072 ushorts
  ushort_t* w1n  = (ushort_t*)(ws + 4587520);    // 131,072 ushorts
  float*    momw = ws + 4653056;                 // 1,024
  float*    decw = ws + 4654080;                 // 1,024
  float*    wfsS = ws + 4655104;                 // 2,048
  float*    wfsM = ws + 4657152;                 // 2,048
  float*    wfsD = ws + 4659200;                 // 2,048
  uint_t*   done = (uint_t*)(ws + 4661248);      // 32 counters

  k_prep<<<dim3(73), dim3(256), 0, stream>>>(Wkv, w0, w1, scale, Wstep, Wmom, Wdec,
      WkvT, w0T, w1T, w1n, wfsS, wfsM, wfsD, done);
  k_pipe2<<<dim3(1280), dim3(256), 0, stream>>>(seq, scale, wfsS, wfsM, wfsD,
      WkvT, w0T, w1T, w1n, fac0, fac1, momw, decw, done, out);
}